// Round 3
// baseline (169.750 us; speedup 1.0000x reference)
//
#include <hip/hip_runtime.h>
#include <math.h>

// Geodesic loss: mean over B of acos(clip((sum_ij m1*m2 - 1)*0.5, -1, 1)).
//
// R7 theory (from R6 counters): the LDS-regroup pipeline was latency-bound,
// NOT HBM-bound -- fully LLC-cached replays ran the same 57us as cold ones
// (2.6 TB/s effective), VALUBusy 5%, occupancy 16%. Cause: hipcc emits
// s_waitcnt vmcnt(0) before every s_barrier, so the two __syncthreads inside
// the consume phase drained the *next* tile's prefetch loads every iteration.
// The register double-buffer never overlapped anything.
//
// Fix: no LDS, no barriers. 4 matrices = 36 floats = 144B = 9 float4,
// contiguous per thread: thread g loads float4[9g..9g+9) of each input and
// owns matrices [4g,4g+4) with no cross-thread regroup. Per wave, each
// 9-instr load group covers a contiguous 9.2KB span so every cache line is
// fully consumed (lane stride 144B costs L1 request rate, not HBM bytes).
// Loads stream continuously; latency hidden by occupancy (no VGPR-hungry
// double buffer -> ~16 waves/CU) instead of a pipeline the barrier
// semantics defeat. Grid 2048x256 = exactly one group per thread at B=2^21.

#define TPB 256
#define NBLOCKS 2048

__global__ __launch_bounds__(TPB) void geo_kernel(
    const float* __restrict__ a, const float* __restrict__ b,
    float* __restrict__ out, float invM, int M)
{
    __shared__ float wsum[TPB / 64];
    const int tid = threadIdx.x;
    float sum = 0.0f;

    const long long G    = (long long)M >> 2;              // groups of 4 matrices
    const long long gid0 = (long long)blockIdx.x * TPB + tid;
    const long long gstr = (long long)gridDim.x * TPB;

    for (long long g = gid0; g < G; g += gstr) {
        const float4* __restrict__ pa = (const float4*)a + 9 * g;
        const float4* __restrict__ pb = (const float4*)b + 9 * g;
        const float4 A0 = pa[0], A1 = pa[1], A2 = pa[2], A3 = pa[3], A4 = pa[4],
                     A5 = pa[5], A6 = pa[6], A7 = pa[7], A8 = pa[8];
        const float4 B0 = pb[0], B1 = pb[1], B2 = pb[2], B3 = pb[3], B4 = pb[4],
                     B5 = pb[5], B6 = pb[6], B7 = pb[7], B8 = pb[8];

        // matrix 0 = floats [0..9) of the 36-float group, etc.
        float d0 = A0.x * B0.x;
        d0 = fmaf(A0.y, B0.y, d0); d0 = fmaf(A0.z, B0.z, d0);
        d0 = fmaf(A0.w, B0.w, d0);
        d0 = fmaf(A1.x, B1.x, d0); d0 = fmaf(A1.y, B1.y, d0);
        d0 = fmaf(A1.z, B1.z, d0); d0 = fmaf(A1.w, B1.w, d0);
        d0 = fmaf(A2.x, B2.x, d0);

        float d1 = A2.y * B2.y;
        d1 = fmaf(A2.z, B2.z, d1); d1 = fmaf(A2.w, B2.w, d1);
        d1 = fmaf(A3.x, B3.x, d1); d1 = fmaf(A3.y, B3.y, d1);
        d1 = fmaf(A3.z, B3.z, d1); d1 = fmaf(A3.w, B3.w, d1);
        d1 = fmaf(A4.x, B4.x, d1); d1 = fmaf(A4.y, B4.y, d1);

        float d2 = A4.z * B4.z;
        d2 = fmaf(A4.w, B4.w, d2);
        d2 = fmaf(A5.x, B5.x, d2); d2 = fmaf(A5.y, B5.y, d2);
        d2 = fmaf(A5.z, B5.z, d2); d2 = fmaf(A5.w, B5.w, d2);
        d2 = fmaf(A6.x, B6.x, d2); d2 = fmaf(A6.y, B6.y, d2);
        d2 = fmaf(A6.z, B6.z, d2);

        float d3 = A6.w * B6.w;
        d3 = fmaf(A7.x, B7.x, d3); d3 = fmaf(A7.y, B7.y, d3);
        d3 = fmaf(A7.z, B7.z, d3); d3 = fmaf(A7.w, B7.w, d3);
        d3 = fmaf(A8.x, B8.x, d3); d3 = fmaf(A8.y, B8.y, d3);
        d3 = fmaf(A8.z, B8.z, d3); d3 = fmaf(A8.w, B8.w, d3);

        sum += acosf(fminf(1.0f, fmaxf(-1.0f, (d0 - 1.0f) * 0.5f)));
        sum += acosf(fminf(1.0f, fmaxf(-1.0f, (d1 - 1.0f) * 0.5f)));
        sum += acosf(fminf(1.0f, fmaxf(-1.0f, (d2 - 1.0f) * 0.5f)));
        sum += acosf(fminf(1.0f, fmaxf(-1.0f, (d3 - 1.0f) * 0.5f)));
    }

    // tail matrices beyond 4*G (empty when M % 4 == 0)
    for (long long m = 4 * G + gid0; m < M; m += gstr) {
        float d = 0.0f;
        #pragma unroll
        for (int j = 0; j < 9; ++j)
            d = fmaf(a[m * 9 + j], b[m * 9 + j], d);
        sum += acosf(fminf(1.0f, fmaxf(-1.0f, (d - 1.0f) * 0.5f)));
    }

    // wave shuffle reduce -> per-block LDS reduce -> one atomic per block
    #pragma unroll
    for (int off = 32; off > 0; off >>= 1)
        sum += __shfl_down(sum, off, 64);
    const int lane = tid & 63;
    const int wid  = tid >> 6;
    if (lane == 0) wsum[wid] = sum;
    __syncthreads();
    if (tid == 0) {
        float s = 0.0f;
        #pragma unroll
        for (int i = 0; i < TPB / 64; ++i) s += wsum[i];
        atomicAdd(out, s * invM);   // device-scope by default
    }
}

extern "C" void kernel_launch(void* const* d_in, const int* in_sizes, int n_in,
                              void* d_out, int out_size, void* d_ws, size_t ws_size,
                              hipStream_t stream) {
    const float* a = (const float*)d_in[0];
    const float* b = (const float*)d_in[1];
    float* out = (float*)d_out;

    const int n = in_sizes[0];   // flat float count = 9*M
    const int M = n / 9;         // number of 3x3 matrices

    // d_out is re-poisoned 0xAA before every timed launch; zero it (async,
    // graph-capture safe), then accumulate the mean with per-block atomics.
    hipMemsetAsync(out, 0, (size_t)out_size * sizeof(float), stream);
    geo_kernel<<<NBLOCKS, TPB, 0, stream>>>(a, b, out, 1.0f / (float)M, M);
}

// Round 4
// 168.959 us; speedup vs baseline: 1.0047x; 1.0047x over previous
//
#include <hip/hip_runtime.h>
#include <math.h>

// Geodesic loss: mean over B of acos(clip((sum_ij m1*m2 - 1)*0.5, -1, 1)).
//
// R8 theory (from R7 counters): R7's per-thread-contiguous 144B-stride
// float4 loads had ZERO intra-instruction coalescing -- every lane hit a
// distinct 64B line, and each line was requested 4x (16B granules) by 4
// different instructions. hbm_gbps pinned at 1.73 TB/s = exactly 1/4 of the
// 6.29 TB/s streaming ceiling -> request-rate-bound, not byte-bound. This
// also explains R2: LLC-cached replays were equally slow (requests, not
// data source, limit). R6's coalesced-load LDS variant was instead killed
// by s_waitcnt vmcnt(0) before every s_barrier (prefetch drained).
//
// Fix: both at once. Each WAVE owns 256 contiguous matrices = 576 float4
// per input: 9 fully-coalesced loads per input (lane stride 16B, 1 request
// per 64B line). Multiply in registers, regroup via a WAVE-PRIVATE LDS
// region: producer wave == consumer wave -> no __syncthreads anywhere in
// the loop -> no vmcnt(0) drains. Explicit lgkmcnt(0) fences order the
// wave's LDS write->read->next-write. LDS reads at 9-float stride (odd ->
// conflict-free); b128 writes at the 2-access/bank floor.
// 36.9KB LDS/block + ~100 VGPR -> ~4 blocks/CU co-resident; 16 waves/CU
// each with 18KB of loads in flight >> Little's-law requirement for 6.3TB/s.

#define TPB 256
#define NBLOCKS 2048
#define MPW 256                  // matrices per wave-iter
#define MPB 1024                 // matrices per block-iter (4 waves)
#define W4_PER_WAVE 576          // float4 per wave per input (256*9/4)
#define LDSF_PER_WAVE 2304       // product floats per wave region

__global__ __launch_bounds__(TPB) void geo_kernel(
    const float* __restrict__ a, const float* __restrict__ b,
    float* __restrict__ out, float invM, int M)
{
    __shared__ float prod[4 * LDSF_PER_WAVE];   // 36 KB, wave-private quarters
    __shared__ float wsum[TPB / 64];

    const int tid  = threadIdx.x;
    const int lane = tid & 63;
    const int wv   = tid >> 6;
    float* lp = prod + wv * LDSF_PER_WAVE;

    float sum = 0.0f;
    const long long NT = (long long)M / MPB;    // full 1024-matrix tiles

    for (long long t = blockIdx.x; t < NT; t += gridDim.x) {
        // 9 coalesced float4 loads per input: lane stride 16B, instr stride 1KB
        const long long base4 = t * (9LL * MPB / 4) + wv * W4_PER_WAVE + lane;
        const float4* __restrict__ pa = (const float4*)a + base4;
        const float4* __restrict__ pb = (const float4*)b + base4;
        const float4 A0 = pa[0],   A1 = pa[64],  A2 = pa[128],
                     A3 = pa[192], A4 = pa[256], A5 = pa[320],
                     A6 = pa[384], A7 = pa[448], A8 = pa[512];
        const float4 B0 = pb[0],   B1 = pb[64],  B2 = pb[128],
                     B3 = pb[192], B4 = pb[256], B5 = pb[320],
                     B6 = pb[384], B7 = pb[448], B8 = pb[512];

        // elementwise products -> wave-private LDS (b128, 16B aligned)
        #define PK(k)                                                       \
        {                                                                   \
            float4 p;                                                       \
            p.x = A##k.x * B##k.x; p.y = A##k.y * B##k.y;                   \
            p.z = A##k.z * B##k.z; p.w = A##k.w * B##k.w;                   \
            *(float4*)&lp[4 * (64 * (k) + lane)] = p;                       \
        }
        PK(0) PK(1) PK(2) PK(3) PK(4) PK(5) PK(6) PK(7) PK(8)
        #undef PK

        // wave-coherent fence: all this wave's ds_writes done before reads.
        // No s_barrier -> no vmcnt(0) drain of other waves' loads.
        asm volatile("s_waitcnt lgkmcnt(0)" ::: "memory");

        // lane reads matrices {lane, 64+lane, 128+lane, 192+lane}:
        // 9-float stride, odd -> conflict-free b32/read2 across the wave
        #pragma unroll
        for (int q = 0; q < 4; ++q) {
            const float* r = lp + 9 * (64 * q + lane);
            float d = ((r[0] + r[1]) + (r[2] + r[3])) +
                      ((r[4] + r[5]) + (r[6] + r[7])) + r[8];
            float cv = fminf(1.0f, fmaxf(-1.0f, (d - 1.0f) * 0.5f));
            sum += acosf(cv);
        }

        // reads complete before next iteration's writes can clobber them
        asm volatile("s_waitcnt lgkmcnt(0)" ::: "memory");
    }

    // tail matrices beyond the last full tile (empty for B=2^21)
    {
        const long long gid    = (long long)blockIdx.x * TPB + tid;
        const long long stride = (long long)gridDim.x * TPB;
        for (long long m = NT * MPB + gid; m < M; m += stride) {
            float d = 0.0f;
            #pragma unroll
            for (int j = 0; j < 9; ++j)
                d = fmaf(a[m * 9 + j], b[m * 9 + j], d);
            float cv = fminf(1.0f, fmaxf(-1.0f, (d - 1.0f) * 0.5f));
            sum += acosf(cv);
        }
    }

    // wave shuffle reduce -> per-block LDS reduce -> one atomic per block
    #pragma unroll
    for (int off = 32; off > 0; off >>= 1)
        sum += __shfl_down(sum, off, 64);
    if ((tid & 63) == 0) wsum[tid >> 6] = sum;
    __syncthreads();
    if (tid == 0) {
        float s = 0.0f;
        #pragma unroll
        for (int i = 0; i < TPB / 64; ++i) s += wsum[i];
        atomicAdd(out, s * invM);   // device-scope by default
    }
}

extern "C" void kernel_launch(void* const* d_in, const int* in_sizes, int n_in,
                              void* d_out, int out_size, void* d_ws, size_t ws_size,
                              hipStream_t stream) {
    const float* a = (const float*)d_in[0];
    const float* b = (const float*)d_in[1];
    float* out = (float*)d_out;

    const int n = in_sizes[0];   // flat float count = 9*M
    const int M = n / 9;         // number of 3x3 matrices

    // d_out is re-poisoned 0xAA before every timed launch; zero it (async,
    // graph-capture safe), then accumulate the mean with per-block atomics.
    hipMemsetAsync(out, 0, (size_t)out_size * sizeof(float), stream);
    geo_kernel<<<NBLOCKS, TPB, 0, stream>>>(a, b, out, 1.0f / (float)M, M);
}